// Round 5
// baseline (277.031 us; speedup 1.0000x reference)
//
#include <hip/hip_runtime.h>

typedef _Float16 f16x8 __attribute__((ext_vector_type(8)));
typedef _Float16 f16x4 __attribute__((ext_vector_type(4)));
typedef float    f32x4 __attribute__((ext_vector_type(4)));
typedef float    f32x16 __attribute__((ext_vector_type(16)));

__device__ __forceinline__ void gload16(const void* g, void* l) {
  __builtin_amdgcn_global_load_lds((const __attribute__((address_space(1))) void*)g,
                                   (__attribute__((address_space(3))) void*)l, 16, 0, 0);
}

// ---------------- elementwise cast fp32 -> fp16 ----------------
__global__ __launch_bounds__(256) void cast_f32_f16(const float* __restrict__ src,
                                                    _Float16* __restrict__ dst, int n4) {
  int i = blockIdx.x * 256 + threadIdx.x;
  if (i < n4) {
    f32x4 v = *(const f32x4*)(src + (size_t)i * 4);
    f16x4 o;
    o[0] = (_Float16)v[0]; o[1] = (_Float16)v[1];
    o[2] = (_Float16)v[2]; o[3] = (_Float16)v[3];
    *(f16x4*)(dst + (size_t)i * 4) = o;
  }
}

// ---------------- merged Wq|Wk|Wv transpose+cast -> WT rows [0,3072) ----------------
__global__ __launch_bounds__(256) void wqkvtrans_kernel(const float* __restrict__ Wq,
                                                        const float* __restrict__ Wk,
                                                        const float* __restrict__ Wv,
                                                        _Float16* __restrict__ dst) {
  const int n0 = blockIdx.x * 64, k0 = blockIdx.y * 64;
  const float* src; int N, nb;
  if (n0 < 2048)      { src = Wq; N = 2048; nb = n0; }
  else if (n0 < 2560) { src = Wk; N = 512;  nb = n0 - 2048; }
  else                { src = Wv; N = 512;  nb = n0 - 2560; }
  __shared__ float tile[64][65];
#pragma unroll
  for (int i = 0; i < 16; ++i) {
    int id = i * 256 + threadIdx.x;
    int kk = id >> 6, nn = id & 63;
    tile[kk][nn] = src[(size_t)(k0 + kk) * N + nb + nn];
  }
  __syncthreads();
#pragma unroll
  for (int i = 0; i < 16; ++i) {
    int id = i * 256 + threadIdx.x;
    int nn = id >> 6, kk = id & 63;
    dst[(size_t)(n0 + nn) * 2048 + k0 + kk] = (_Float16)tile[kk][nn];
  }
}

// ---------------- transpose + cast (single source, for Wo) ----------------
__global__ __launch_bounds__(256) void wtrans_kernel(const float* __restrict__ src,
                                                     _Float16* __restrict__ dst,
                                                     int N, int K, int rowOff, int ldDst) {
  const int n0 = blockIdx.x * 64, k0 = blockIdx.y * 64;
  __shared__ float tile[64][65];
#pragma unroll
  for (int i = 0; i < 16; ++i) {
    int id = i * 256 + threadIdx.x;
    int kk = id >> 6, nn = id & 63;
    tile[kk][nn] = src[(size_t)(k0 + kk) * N + n0 + nn];
  }
  __syncthreads();
#pragma unroll
  for (int i = 0; i < 16; ++i) {
    int id = i * 256 + threadIdx.x;
    int nn = id >> 6, kk = id & 63;
    dst[(size_t)(rowOff + n0 + nn) * ldDst + k0 + kk] = (_Float16)tile[kk][nn];
  }
}

// ---------------- pack bq|bk|bv ----------------
__global__ __launch_bounds__(256) void biaspack_kernel(const float* __restrict__ bq,
                                                       const float* __restrict__ bk,
                                                       const float* __restrict__ bv,
                                                       float* __restrict__ out) {
  int i = blockIdx.x * 256 + threadIdx.x;
  if (i < 3072) out[i] = (i < 2048) ? bq[i] : (i < 2560 ? bk[i - 2048] : bv[i - 2560]);
}

// ---------------- GEMM: C = A(MxK) * B^T(NxK) + bias ----------------
template <bool F16OUT>
__global__ __launch_bounds__(256) void gemm_nt(const _Float16* __restrict__ A,
                                               const _Float16* __restrict__ B,
                                               const float* __restrict__ bias,
                                               void* __restrict__ Cv,
                                               int M, int N, int K) {
  __shared__ __align__(16) _Float16 As[128][64];
  __shared__ __align__(16) _Float16 Bs[128][64];
  const int tid = threadIdx.x;
  const int lane = tid & 63, wave = tid >> 6;
  const int wr = wave >> 1, wc = wave & 1;
  const int r = lane & 15, g = lane >> 4;
  const int rb = blockIdx.y * 128, cb = blockIdx.x * 128;

  const int swz = ((tid & 7) ^ ((tid >> 3) & 7)) * 8;
  const _Float16* aSrc = A + (size_t)(rb + (tid >> 3)) * K + swz;
  const _Float16* bSrc = B + (size_t)(cb + (tid >> 3)) * K + swz;

  f32x4 acc[4][4] = {};

  for (int kt = 0; kt < K; kt += 64) {
    __syncthreads();
#pragma unroll
    for (int p = 0; p < 4; ++p) {
      gload16(aSrc + (size_t)(p * 32) * K + kt, (_Float16*)As + (p * 256 + wave * 64) * 8);
      gload16(bSrc + (size_t)(p * 32) * K + kt, (_Float16*)Bs + (p * 256 + wave * 64) * 8);
    }
    __syncthreads();
#pragma unroll
    for (int kk = 0; kk < 2; ++kk) {
      f16x8 af[4], bf[4];
#pragma unroll
      for (int m = 0; m < 4; ++m) {
        int row = wr * 64 + m * 16 + r;
        af[m] = *(const f16x8*)(&As[row][((kk * 4 + g) ^ (row & 7)) * 8]);
      }
#pragma unroll
      for (int n = 0; n < 4; ++n) {
        int row = wc * 64 + n * 16 + r;
        bf[n] = *(const f16x8*)(&Bs[row][((kk * 4 + g) ^ (row & 7)) * 8]);
      }
#pragma unroll
      for (int m = 0; m < 4; ++m)
#pragma unroll
        for (int n = 0; n < 4; ++n)
          acc[m][n] = __builtin_amdgcn_mfma_f32_16x16x32_f16(af[m], bf[n], acc[m][n], 0, 0, 0);
    }
  }

  float bvals[4];
#pragma unroll
  for (int n = 0; n < 4; ++n) bvals[n] = bias[cb + wc * 64 + n * 16 + r];
#pragma unroll
  for (int m = 0; m < 4; ++m) {
#pragma unroll
    for (int n = 0; n < 4; ++n) {
#pragma unroll
      for (int j = 0; j < 4; ++j) {
        int row = rb + wr * 64 + m * 16 + g * 4 + j;
        int col = cb + wc * 64 + n * 16 + r;
        float v = acc[m][n][j] + bvals[n];
        if (F16OUT)
          ((_Float16*)Cv)[(size_t)row * N + col] = (_Float16)v;
        else
          ((float*)Cv)[(size_t)row * N + col] = v;
      }
    }
  }
}

// ---------------- RoPE in-place on QKV (vectorized f16x8) ----------------
__global__ __launch_bounds__(256) void rope_kernel(_Float16* __restrict__ QKV) {
  const int tok = blockIdx.x;
  const int t = tok & 2047;
  __shared__ float cs[64], sn[64];
  if (threadIdx.x < 64) {
    int j = threadIdx.x;
    float freq = exp2f((float)(-2 * j) * (19.931568569324174f / 128.0f));
    float ang = (float)t * freq;
    cs[j] = cosf(ang);
    sn[j] = sinf(ang);
  }
  __syncthreads();
  _Float16* base = QKV + (size_t)tok * 3072;
  int idx = threadIdx.x;
  if (idx < 160) {
    int head = idx >> 3, j0 = (idx & 7) * 8;
    int cb = (head < 16) ? head * 128 : 2048 + (head - 16) * 128;
    _Float16* p = base + cb;
    f16x8 a = *(const f16x8*)(p + j0);
    f16x8 b2 = *(const f16x8*)(p + 64 + j0);
    f16x8 oa, ob;
#pragma unroll
    for (int e = 0; e < 8; ++e) {
      float c = cs[j0 + e], s = sn[j0 + e];
      float x1 = (float)a[e], x2 = (float)b2[e];
      oa[e] = (_Float16)(x1 * c - x2 * s);
      ob[e] = (_Float16)(x2 * c + x1 * s);
    }
    *(f16x8*)(p + j0) = oa;
    *(f16x8*)(p + 64 + j0) = ob;
  }
}

// ---------------- transpose V slabs -> Vt[(b*4+kvh)][d][t] ----------------
__global__ __launch_bounds__(256) void vtrans_kernel(const _Float16* __restrict__ QKV,
                                                     _Float16* __restrict__ Vt) {
  const int bk = blockIdx.z;
  const int t0 = blockIdx.x * 64, d0 = blockIdx.y * 64;
  const int b = bk >> 2, kvh = bk & 3;
  __shared__ _Float16 tile[64][65];
  const _Float16* src = QKV + (size_t)b * 2048 * 3072 + 2560 + kvh * 128;
#pragma unroll
  for (int i = 0; i < 16; ++i) {
    int id = i * 256 + threadIdx.x;
    int tt = id >> 6, dd = id & 63;
    tile[tt][dd] = src[(size_t)(t0 + tt) * 3072 + d0 + dd];
  }
  __syncthreads();
  _Float16* dst = Vt + (size_t)bk * 128 * 2048;
#pragma unroll
  for (int i = 0; i < 16; ++i) {
    int id = i * 256 + threadIdx.x;
    int dd = id >> 6, tt = id & 63;
    dst[(size_t)(d0 + dd) * 2048 + t0 + tt] = tile[tt][dd];
  }
}

// ---------------- causal GQA flash attention v5: 32x32 MFMA, 32q/wave ----------------
// QBLK=128, 4 waves x 32q, grid 512 with complementary qt pairing. Single-buffer
// K[64][128] + V^T[128][64] LDS (48KB -> 3 blocks/CU). 2x arithmetic intensity
// per LDS byte vs 16x16 path (the r4-measured LDS-BW bound).
__global__ __launch_bounds__(256) void attn_kernel(const _Float16* __restrict__ QKV,
                                                   const _Float16* __restrict__ Vt,
                                                   _Float16* __restrict__ O) {
  const int bid = blockIdx.x;
  const int b = bid >> 8;
  const int ii = bid & 255;
  const int h = ii >> 4;
  const int qtr = ii & 15;
  const int qt = b ? 15 - qtr : qtr;
  const int tid = threadIdx.x;
  const int wave = tid >> 6, lane = tid & 63;
  const int l31 = lane & 31, hi = lane >> 5;
  const int q0w = qt * 128 + wave * 32;
  const int kvh = h >> 2;
  const _Float16* Qb  = QKV + (size_t)b * 2048 * 3072 + h * 128;
  const _Float16* Kb  = QKV + (size_t)b * 2048 * 3072 + 2048 + kvh * 128;
  const _Float16* Vtg = Vt + (size_t)(b * 4 + kvh) * 128 * 2048;

  __shared__ __align__(16) _Float16 Klds[64][128];   // [k][d], LDS chunk c holds global chunk c^(k&7)
  __shared__ __align__(16) _Float16 Vlds[128][64];   // [d][k], chunk c holds global c^(d&7)
  __shared__ __align__(16) _Float16 Plds[4][32][64]; // per-wave P[q][k], chunk swz c^(q&7)

  // pre-swizzled staging sources (linear LDS dest + swizzled read, rule #21)
  const _Float16* kSrc = Kb  + (size_t)(tid >> 4) * 3072 + (((tid & 15) ^ ((tid >> 4) & 7)) * 8);
  const _Float16* vSrc = Vtg + (size_t)(tid >> 3) * 2048 + (((tid & 7) ^ ((tid >> 3) & 7)) * 8);

  // Q frags (B-operand): lane holds Q[q0w+l31][ds*16 + hi*8 + e], scale*log2e folded
  f16x8 qf[8];
  {
    const float qsc = 0.08838834764831845f * 1.4426950408889634f;
    const _Float16* qrow = Qb + (size_t)(q0w + l31) * 3072 + hi * 8;
#pragma unroll
    for (int ds = 0; ds < 8; ++ds) {
      f16x8 v = *(const f16x8*)(qrow + ds * 16);
#pragma unroll
      for (int e = 0; e < 8; ++e) v[e] = (_Float16)((float)v[e] * qsc);
      qf[ds] = v;
    }
  }

  f32x16 oacc[4] = {};  // [dsub]: D rows = q-pattern, col d = dsub*32 + l31
  float mrun = -1e30f, lrun = 0.f;
  const int kend = qt * 128 + 128;
  const int qlim = q0w + 32;

  for (int kb = 0; kb < kend; kb += 64) {
#pragma unroll
    for (int p = 0; p < 4; ++p) {
      gload16(kSrc + (size_t)(kb + p * 16) * 3072, (_Float16*)Klds + (p * 256 + tid) * 8);
      gload16(vSrc + (size_t)(p * 32) * 2048 + kb, (_Float16*)Vlds + (p * 256 + tid) * 8);
    }
    __syncthreads();  // staged tiles visible
    if (kb < qlim) {
      // S^T = mfma32(A=K, B=Q): D[k-pattern][q=l31], 2 ksub x 8 dsub
      f32x16 sT[2] = {};
      __builtin_amdgcn_s_setprio(1);
#pragma unroll
      for (int ds = 0; ds < 8; ++ds) {
#pragma unroll
        for (int ks = 0; ks < 2; ++ks) {
          f16x8 kf = *(const f16x8*)(&Klds[ks * 32 + l31][(((ds * 2 + hi) ^ (l31 & 7)) * 8)]);
          sT[ks] = __builtin_amdgcn_mfma_f32_32x32x16_f16(kf, qf[ds], sT[ks], 0, 0, 0);
        }
      }
      __builtin_amdgcn_s_setprio(0);
      // causal mask (near-diagonal tiles only): lane's k = kb+ks*32+(r&3)+8*(r>>2)+4*hi, q = q0w+l31
      if (kb + 63 > q0w) {
#pragma unroll
        for (int ks = 0; ks < 2; ++ks)
#pragma unroll
          for (int r = 0; r < 16; ++r) {
            int kg = kb + ks * 32 + (r & 3) + 8 * (r >> 2) + 4 * hi;
            if (kg > q0w + l31) sT[ks][r] = -1e30f;
          }
      }
      float mt = -1e30f;
#pragma unroll
      for (int ks = 0; ks < 2; ++ks)
#pragma unroll
        for (int r = 0; r < 16; ++r) mt = fmaxf(mt, sT[ks][r]);
      mt = fmaxf(mt, __shfl_xor(mt, 32));  // partner holds the other 32 k's of this q
      if (__any(mt > mrun)) {  // defer-max
        float mnew = fmaxf(mrun, mt);
        float alpha = exp2f(mrun - mnew);
        lrun *= alpha;
#pragma unroll
        for (int r = 0; r < 16; ++r) {
          float al = __shfl(alpha, (r & 3) + 8 * (r >> 2) + 4 * hi);  // alpha of O-row's q
#pragma unroll
          for (int dsub = 0; dsub < 4; ++dsub) oacc[dsub][r] *= al;
        }
        mrun = mnew;
      }
      float pv[2][16];
      float rs = 0.f;
#pragma unroll
      for (int ks = 0; ks < 2; ++ks)
#pragma unroll
        for (int r = 0; r < 16; ++r) {
          pv[ks][r] = exp2f(sT[ks][r] - mrun);
          rs += pv[ks][r];
        }
      rs += __shfl_xor(rs, 32);
      lrun += rs;
      // P -> LDS (wave-internal). Reg r -> k = ks*32 + 8*(r>>2) + (r&3) + 4*hi:
      // regs 4m..4m+3 are 4 consecutive k at base ks*32+8m+4hi -> one f16x4 store.
      asm volatile("" ::: "memory");
#pragma unroll
      for (int ks = 0; ks < 2; ++ks)
#pragma unroll
        for (int m = 0; m < 4; ++m) {
          f16x4 w;
#pragma unroll
          for (int j = 0; j < 4; ++j) w[j] = (_Float16)pv[ks][m * 4 + j];
          int c = (ks * 4 + m) ^ (l31 & 7);
          *(f16x4*)(&Plds[wave][l31][c * 8 + hi * 4]) = w;
        }
      asm volatile("s_waitcnt lgkmcnt(0)" ::: "memory");
      __builtin_amdgcn_sched_barrier(0);
      // O += P @ V : A=P[q=l31][16s+8hi+e], B=V^T rows (col d=l31)
      __builtin_amdgcn_s_setprio(1);
#pragma unroll
      for (int s = 0; s < 4; ++s) {
        f16x8 pa = *(const f16x8*)(&Plds[wave][l31][(((s * 2 + hi) ^ (l31 & 7)) * 8)]);
#pragma unroll
        for (int dsub = 0; dsub < 4; ++dsub) {
          f16x8 vf = *(const f16x8*)(&Vlds[dsub * 32 + l31][(((s * 2 + hi) ^ (l31 & 7)) * 8)]);
          oacc[dsub] = __builtin_amdgcn_mfma_f32_32x32x16_f16(pa, vf, oacc[dsub], 0, 0, 0);
        }
      }
      __builtin_amdgcn_s_setprio(0);
    }
    __syncthreads();  // protect K/V LDS before next stage
  }

  // epilogue: O[q][h*128 + dsub*32 + l31], q = (r&3)+8*(r>>2)+4*hi
  float linv = 1.0f / lrun;
#pragma unroll
  for (int r = 0; r < 16; ++r) {
    int qrow = (r & 3) + 8 * (r >> 2) + 4 * hi;
    float li = __shfl(linv, qrow);
    _Float16* orow = O + (size_t)(b * 2048 + q0w + qrow) * 2048 + h * 128 + l31;
#pragma unroll
    for (int dsub = 0; dsub < 4; ++dsub)
      orow[dsub * 32] = (_Float16)(oacc[dsub][r] * li);
  }
}

// ---------------- launch ----------------
extern "C" void kernel_launch(void* const* d_in, const int* in_sizes, int n_in,
                              void* d_out, int out_size, void* d_ws, size_t ws_size,
                              hipStream_t stream) {
  const float* x  = (const float*)d_in[0];
  const float* Wq = (const float*)d_in[1];
  const float* bq = (const float*)d_in[2];
  const float* Wk = (const float*)d_in[3];
  const float* bk = (const float*)d_in[4];
  const float* Wv = (const float*)d_in[5];
  const float* bv = (const float*)d_in[6];
  const float* Wo = (const float*)d_in[7];
  const float* bo = (const float*)d_in[8];
  float* out = (float*)d_out;

  char* ws = (char*)d_ws;
  constexpr size_t QKV_OFF  = 0;                       // 25165824
  constexpr size_t VT_OFF   = 25165824;                // 4194304
  constexpr size_t ATTN_OFF = VT_OFF + 4194304;        // 16777216
  constexpr size_t WT_OFF   = ATTN_OFF + 16777216;     // 12582912
  constexpr size_t BIAS_OFF = WT_OFF + 12582912;
  _Float16* QKV  = (_Float16*)(ws + QKV_OFF);
  _Float16* Vt   = (_Float16*)(ws + VT_OFF);
  _Float16* attn = (_Float16*)(ws + ATTN_OFF);
  _Float16* WT   = (_Float16*)(ws + WT_OFF);
  float*    bqkv = (float*)(ws + BIAS_OFF);
  _Float16* xb = (_Float16*)d_out;  // dead before final GEMM writes d_out

  cast_f32_f16<<<8192, 256, 0, stream>>>(x, xb, (2 * 2048 * 2048) / 4);
  wqkvtrans_kernel<<<dim3(48, 32), 256, 0, stream>>>(Wq, Wk, Wv, WT);
  biaspack_kernel<<<12, 256, 0, stream>>>(bq, bk, bv, bqkv);
  gemm_nt<true><<<dim3(3072 / 128, 4096 / 128), 256, 0, stream>>>(xb, WT, bqkv, QKV, 4096, 3072, 2048);
  wtrans_kernel<<<dim3(32, 32), 256, 0, stream>>>(Wo, WT, 2048, 2048, 0, 2048);
  rope_kernel<<<4096, 256, 0, stream>>>(QKV);
  vtrans_kernel<<<dim3(32, 2, 8), 256, 0, stream>>>(QKV, Vt);
  attn_kernel<<<512, 256, 0, stream>>>(QKV, Vt, attn);
  gemm_nt<false><<<dim3(2048 / 128, 4096 / 128), 256, 0, stream>>>(attn, WT, bo, out, 4096, 2048, 2048);
}

// Round 6
// 226.352 us; speedup vs baseline: 1.2239x; 1.2239x over previous
//
#include <hip/hip_runtime.h>

typedef _Float16 f16x8 __attribute__((ext_vector_type(8)));
typedef _Float16 f16x4 __attribute__((ext_vector_type(4)));
typedef float    f32x4 __attribute__((ext_vector_type(4)));

__device__ __forceinline__ void gload16(const void* g, void* l) {
  __builtin_amdgcn_global_load_lds((const __attribute__((address_space(1))) void*)g,
                                   (__attribute__((address_space(3))) void*)l, 16, 0, 0);
}

// ---------------- elementwise cast fp32 -> fp16 ----------------
__global__ __launch_bounds__(256) void cast_f32_f16(const float* __restrict__ src,
                                                    _Float16* __restrict__ dst, int n4) {
  int i = blockIdx.x * 256 + threadIdx.x;
  if (i < n4) {
    f32x4 v = *(const f32x4*)(src + (size_t)i * 4);
    f16x4 o;
    o[0] = (_Float16)v[0]; o[1] = (_Float16)v[1];
    o[2] = (_Float16)v[2]; o[3] = (_Float16)v[3];
    *(f16x4*)(dst + (size_t)i * 4) = o;
  }
}

// ---------------- merged Wq|Wk|Wv transpose+cast -> WT rows [0,3072) ----------------
__global__ __launch_bounds__(256) void wqkvtrans_kernel(const float* __restrict__ Wq,
                                                        const float* __restrict__ Wk,
                                                        const float* __restrict__ Wv,
                                                        _Float16* __restrict__ dst) {
  const int n0 = blockIdx.x * 64, k0 = blockIdx.y * 64;
  const float* src; int N, nb;
  if (n0 < 2048)      { src = Wq; N = 2048; nb = n0; }
  else if (n0 < 2560) { src = Wk; N = 512;  nb = n0 - 2048; }
  else                { src = Wv; N = 512;  nb = n0 - 2560; }
  __shared__ float tile[64][65];
#pragma unroll
  for (int i = 0; i < 16; ++i) {
    int id = i * 256 + threadIdx.x;
    int kk = id >> 6, nn = id & 63;
    tile[kk][nn] = src[(size_t)(k0 + kk) * N + nb + nn];
  }
  __syncthreads();
#pragma unroll
  for (int i = 0; i < 16; ++i) {
    int id = i * 256 + threadIdx.x;
    int nn = id >> 6, kk = id & 63;
    dst[(size_t)(n0 + nn) * 2048 + k0 + kk] = (_Float16)tile[kk][nn];
  }
}

// ---------------- transpose + cast (single source, for Wo) ----------------
__global__ __launch_bounds__(256) void wtrans_kernel(const float* __restrict__ src,
                                                     _Float16* __restrict__ dst,
                                                     int N, int K, int rowOff, int ldDst) {
  const int n0 = blockIdx.x * 64, k0 = blockIdx.y * 64;
  __shared__ float tile[64][65];
#pragma unroll
  for (int i = 0; i < 16; ++i) {
    int id = i * 256 + threadIdx.x;
    int kk = id >> 6, nn = id & 63;
    tile[kk][nn] = src[(size_t)(k0 + kk) * N + n0 + nn];
  }
  __syncthreads();
#pragma unroll
  for (int i = 0; i < 16; ++i) {
    int id = i * 256 + threadIdx.x;
    int nn = id >> 6, kk = id & 63;
    dst[(size_t)(rowOff + n0 + nn) * ldDst + k0 + kk] = (_Float16)tile[kk][nn];
  }
}

// ---------------- pack bq|bk|bv ----------------
__global__ __launch_bounds__(256) void biaspack_kernel(const float* __restrict__ bq,
                                                       const float* __restrict__ bk,
                                                       const float* __restrict__ bv,
                                                       float* __restrict__ out) {
  int i = blockIdx.x * 256 + threadIdx.x;
  if (i < 3072) out[i] = (i < 2048) ? bq[i] : (i < 2560 ? bk[i - 2048] : bv[i - 2560]);
}

// ---------------- zero the attn work-queue counter (per launch, replay-safe) ----
__global__ void zeroctr_kernel(int* c) { *c = 0; }

// ---------------- GEMM: C = A(MxK) * B^T(NxK) + bias ----------------
template <bool F16OUT>
__global__ __launch_bounds__(256) void gemm_nt(const _Float16* __restrict__ A,
                                               const _Float16* __restrict__ B,
                                               const float* __restrict__ bias,
                                               void* __restrict__ Cv,
                                               int M, int N, int K) {
  __shared__ __align__(16) _Float16 As[128][64];
  __shared__ __align__(16) _Float16 Bs[128][64];
  const int tid = threadIdx.x;
  const int lane = tid & 63, wave = tid >> 6;
  const int wr = wave >> 1, wc = wave & 1;
  const int r = lane & 15, g = lane >> 4;
  const int rb = blockIdx.y * 128, cb = blockIdx.x * 128;

  const int swz = ((tid & 7) ^ ((tid >> 3) & 7)) * 8;
  const _Float16* aSrc = A + (size_t)(rb + (tid >> 3)) * K + swz;
  const _Float16* bSrc = B + (size_t)(cb + (tid >> 3)) * K + swz;

  f32x4 acc[4][4] = {};

  for (int kt = 0; kt < K; kt += 64) {
    __syncthreads();
#pragma unroll
    for (int p = 0; p < 4; ++p) {
      gload16(aSrc + (size_t)(p * 32) * K + kt, (_Float16*)As + (p * 256 + wave * 64) * 8);
      gload16(bSrc + (size_t)(p * 32) * K + kt, (_Float16*)Bs + (p * 256 + wave * 64) * 8);
    }
    __syncthreads();
#pragma unroll
    for (int kk = 0; kk < 2; ++kk) {
      f16x8 af[4], bf[4];
#pragma unroll
      for (int m = 0; m < 4; ++m) {
        int row = wr * 64 + m * 16 + r;
        af[m] = *(const f16x8*)(&As[row][((kk * 4 + g) ^ (row & 7)) * 8]);
      }
#pragma unroll
      for (int n = 0; n < 4; ++n) {
        int row = wc * 64 + n * 16 + r;
        bf[n] = *(const f16x8*)(&Bs[row][((kk * 4 + g) ^ (row & 7)) * 8]);
      }
#pragma unroll
      for (int m = 0; m < 4; ++m)
#pragma unroll
        for (int n = 0; n < 4; ++n)
          acc[m][n] = __builtin_amdgcn_mfma_f32_16x16x32_f16(af[m], bf[n], acc[m][n], 0, 0, 0);
    }
  }

  float bvals[4];
#pragma unroll
  for (int n = 0; n < 4; ++n) bvals[n] = bias[cb + wc * 64 + n * 16 + r];
#pragma unroll
  for (int m = 0; m < 4; ++m) {
#pragma unroll
    for (int n = 0; n < 4; ++n) {
#pragma unroll
      for (int j = 0; j < 4; ++j) {
        int row = rb + wr * 64 + m * 16 + g * 4 + j;
        int col = cb + wc * 64 + n * 16 + r;
        float v = acc[m][n][j] + bvals[n];
        if (F16OUT)
          ((_Float16*)Cv)[(size_t)row * N + col] = (_Float16)v;
        else
          ((float*)Cv)[(size_t)row * N + col] = v;
      }
    }
  }
}

// ---------------- RoPE in-place on QKV (vectorized f16x8) ----------------
__global__ __launch_bounds__(256) void rope_kernel(_Float16* __restrict__ QKV) {
  const int tok = blockIdx.x;
  const int t = tok & 2047;
  __shared__ float cs[64], sn[64];
  if (threadIdx.x < 64) {
    int j = threadIdx.x;
    float freq = exp2f((float)(-2 * j) * (19.931568569324174f / 128.0f));
    float ang = (float)t * freq;
    cs[j] = cosf(ang);
    sn[j] = sinf(ang);
  }
  __syncthreads();
  _Float16* base = QKV + (size_t)tok * 3072;
  int idx = threadIdx.x;
  if (idx < 160) {
    int head = idx >> 3, j0 = (idx & 7) * 8;
    int cb = (head < 16) ? head * 128 : 2048 + (head - 16) * 128;
    _Float16* p = base + cb;
    f16x8 a = *(const f16x8*)(p + j0);
    f16x8 b2 = *(const f16x8*)(p + 64 + j0);
    f16x8 oa, ob;
#pragma unroll
    for (int e = 0; e < 8; ++e) {
      float c = cs[j0 + e], s = sn[j0 + e];
      float x1 = (float)a[e], x2 = (float)b2[e];
      oa[e] = (_Float16)(x1 * c - x2 * s);
      ob[e] = (_Float16)(x2 * c + x1 * s);
    }
    *(f16x8*)(p + j0) = oa;
    *(f16x8*)(p + 64 + j0) = ob;
  }
}

// ---------------- transpose V slabs -> Vt[(b*4+kvh)][d][t] ----------------
__global__ __launch_bounds__(256) void vtrans_kernel(const _Float16* __restrict__ QKV,
                                                     _Float16* __restrict__ Vt) {
  const int bk = blockIdx.z;
  const int t0 = blockIdx.x * 64, d0 = blockIdx.y * 64;
  const int b = bk >> 2, kvh = bk & 3;
  __shared__ _Float16 tile[64][65];
  const _Float16* src = QKV + (size_t)b * 2048 * 3072 + 2560 + kvh * 128;
#pragma unroll
  for (int i = 0; i < 16; ++i) {
    int id = i * 256 + threadIdx.x;
    int tt = id >> 6, dd = id & 63;
    tile[tt][dd] = src[(size_t)(t0 + tt) * 3072 + d0 + dd];
  }
  __syncthreads();
  _Float16* dst = Vt + (size_t)bk * 128 * 2048;
#pragma unroll
  for (int i = 0; i < 16; ++i) {
    int id = i * 256 + threadIdx.x;
    int dd = id >> 6, tt = id & 63;
    dst[(size_t)(d0 + dd) * 2048 + t0 + tt] = tile[tt][dd];
  }
}

// ---------------- causal GQA flash attention v6: dynamic work queue ----------------
// 1024 items (b,h,qt64) pulled off a global counter in descending-qt (LPT) order
// -> placement-independent load balance. 4 waves x 16q, 16x16 MFMA (r2-verified
// math), single-buffered K[64][128]+V^T[128][64] LDS, 40KB -> 4 blocks/CU.
__global__ __launch_bounds__(256) void attn_kernel(const _Float16* __restrict__ QKV,
                                                   const _Float16* __restrict__ Vt,
                                                   _Float16* __restrict__ O,
                                                   int* __restrict__ ctr) {
  const int tid = threadIdx.x;
  const int wave = tid >> 6, lane = tid & 63;
  const int r = lane & 15, g = lane >> 4;

  __shared__ __align__(16) _Float16 Klds[64][128];   // [k][d], chunk c holds global c^(k&7)
  __shared__ __align__(16) _Float16 Vlds[128][64];   // [d][k], chunk c holds global c^(d&7)
  __shared__ __align__(16) _Float16 Plds[4][16][64];
  __shared__ int wslot;

  const int kRowOff = tid >> 4, kChunk = ((tid & 15) ^ ((tid >> 4) & 7)) * 8;
  const int vRowOff = tid >> 3, vChunk = ((tid & 7) ^ ((tid >> 3) & 7)) * 8;

  for (;;) {
    __syncthreads();                 // LDS + wslot reuse guard
    if (tid == 0) wslot = atomicAdd(ctr, 1);
    __syncthreads();
    const int w = wslot;
    if (w >= 1024) break;
    const int qt = 31 - (w >> 5);    // heavy items first (LPT)
    const int rem = w & 31;
    const int b = rem >> 4, h = rem & 15;
    const int kvh = h >> 2;
    const int q0 = qt * 64 + wave * 16;
    const _Float16* Qb  = QKV + (size_t)b * 2048 * 3072 + h * 128;
    const _Float16* Kb  = QKV + (size_t)b * 2048 * 3072 + 2048 + kvh * 128;
    const _Float16* Vtg = Vt + (size_t)(b * 4 + kvh) * 128 * 2048;
    const _Float16* kSrc = Kb  + (size_t)kRowOff * 3072 + kChunk;
    const _Float16* vSrc = Vtg + (size_t)vRowOff * 2048 + vChunk;

    // Q fragments, scale*log2e folded (exp2-domain softmax)
    f16x8 qf[4];
    {
      const float qsc = 0.08838834764831845f * 1.4426950408889634f;
      const _Float16* qrow = Qb + (size_t)(q0 + r) * 3072 + g * 8;
#pragma unroll
      for (int c = 0; c < 4; ++c) {
        f16x8 v = *(const f16x8*)(qrow + c * 32);
#pragma unroll
        for (int i = 0; i < 8; ++i) v[i] = (_Float16)((float)v[i] * qsc);
        qf[c] = v;
      }
    }

    f32x4 oacc[8] = {};
    float mrun = -1e30f, lrun = 0.f;
    const int kend = qt * 64 + 64;
    const int qlim = q0 + 16;

    for (int kb = 0; kb < kend; kb += 64) {
#pragma unroll
      for (int p = 0; p < 4; ++p) {
        gload16(kSrc + (size_t)(kb + p * 16) * 3072, (_Float16*)Klds + (p * 256 + wave * 64) * 8);
        gload16(vSrc + (size_t)(p * 32) * 2048 + kb, (_Float16*)Vlds + (p * 256 + wave * 64) * 8);
      }
      __syncthreads();  // staged tiles visible
      if (kb < qlim) {
        // S^T = K_tile @ Q^T : lane holds S[k=n*16+g*4+j][q=r]
        f32x4 sT[4] = {};
        __builtin_amdgcn_s_setprio(1);
#pragma unroll
        for (int c = 0; c < 4; ++c) {
#pragma unroll
          for (int n = 0; n < 4; ++n) {
            f16x8 kf = *(const f16x8*)(&Klds[n * 16 + r][(((c * 4 + g) ^ (r & 7)) * 8)]);
            sT[n] = __builtin_amdgcn_mfma_f32_16x16x32_f16(kf, qf[c], sT[n], 0, 0, 0);
          }
        }
        __builtin_amdgcn_s_setprio(0);
        if (kb + 63 > q0) {  // causal mask, near-diagonal tiles only
#pragma unroll
          for (int n = 0; n < 4; ++n)
#pragma unroll
            for (int j = 0; j < 4; ++j) {
              int kg = kb + n * 16 + g * 4 + j;
              if (kg > q0 + r) sT[n][j] = -1e30f;
            }
        }
        float mt = -1e30f;
#pragma unroll
        for (int n = 0; n < 4; ++n)
#pragma unroll
          for (int j = 0; j < 4; ++j) mt = fmaxf(mt, sT[n][j]);
        mt = fmaxf(mt, __shfl_xor(mt, 16));
        mt = fmaxf(mt, __shfl_xor(mt, 32));
        if (__any(mt > mrun)) {  // defer-max
          float mnew = fmaxf(mrun, mt);
          float alpha = exp2f(mrun - mnew);
          lrun *= alpha;
          float al[4];
#pragma unroll
          for (int jj = 0; jj < 4; ++jj) al[jj] = __shfl(alpha, g * 4 + jj);
#pragma unroll
          for (int dt = 0; dt < 8; ++dt)
#pragma unroll
            for (int jj = 0; jj < 4; ++jj) oacc[dt][jj] *= al[jj];
          mrun = mnew;
        }
        float p[4][4];
        float rs = 0.f;
#pragma unroll
        for (int n = 0; n < 4; ++n)
#pragma unroll
          for (int j = 0; j < 4; ++j) {
            p[n][j] = exp2f(sT[n][j] - mrun);
            rs += p[n][j];
          }
        rs += __shfl_xor(rs, 16);
        rs += __shfl_xor(rs, 32);
        lrun += rs;
        // P -> LDS (16B-chunk swizzle), wave-internal round trip
        asm volatile("" ::: "memory");
#pragma unroll
        for (int n = 0; n < 4; ++n) {
          f16x4 p4;
#pragma unroll
          for (int j = 0; j < 4; ++j) p4[j] = (_Float16)p[n][j];
          int c16s = (2 * n + (g >> 1)) ^ (r & 7);
          *(f16x4*)(&Plds[wave][r][c16s * 8 + (g & 1) * 4]) = p4;
        }
        asm volatile("s_waitcnt lgkmcnt(0)" ::: "memory");
        __builtin_amdgcn_sched_barrier(0);
        f16x8 pa0 = *(const f16x8*)(&Plds[wave][r][((g) ^ (r & 7)) * 8]);
        f16x8 pa1 = *(const f16x8*)(&Plds[wave][r][((4 + g) ^ (r & 7)) * 8]);
        __builtin_amdgcn_s_setprio(1);
#pragma unroll
        for (int dt = 0; dt < 8; ++dt) {
          f16x8 vf0 = *(const f16x8*)(&Vlds[dt * 16 + r][((g) ^ (r & 7)) * 8]);
          oacc[dt] = __builtin_amdgcn_mfma_f32_16x16x32_f16(pa0, vf0, oacc[dt], 0, 0, 0);
          f16x8 vf1 = *(const f16x8*)(&Vlds[dt * 16 + r][((4 + g) ^ (r & 7)) * 8]);
          oacc[dt] = __builtin_amdgcn_mfma_f32_16x16x32_f16(pa1, vf1, oacc[dt], 0, 0, 0);
        }
        __builtin_amdgcn_s_setprio(0);
      }
      __syncthreads();  // protect K/V LDS before next stage
    }

    float linv = 1.0f / lrun;
    float li[4];
#pragma unroll
    for (int jj = 0; jj < 4; ++jj) li[jj] = __shfl(linv, g * 4 + jj);
#pragma unroll
    for (int dt = 0; dt < 8; ++dt)
#pragma unroll
      for (int jj = 0; jj < 4; ++jj)
        O[(size_t)(b * 2048 + q0 + g * 4 + jj) * 2048 + h * 128 + dt * 16 + r] =
            (_Float16)(oacc[dt][jj] * li[jj]);
  }
}

// ---------------- launch ----------------
extern "C" void kernel_launch(void* const* d_in, const int* in_sizes, int n_in,
                              void* d_out, int out_size, void* d_ws, size_t ws_size,
                              hipStream_t stream) {
  const float* x  = (const float*)d_in[0];
  const float* Wq = (const float*)d_in[1];
  const float* bq = (const float*)d_in[2];
  const float* Wk = (const float*)d_in[3];
  const float* bk = (const float*)d_in[4];
  const float* Wv = (const float*)d_in[5];
  const float* bv = (const float*)d_in[6];
  const float* Wo = (const float*)d_in[7];
  const float* bo = (const float*)d_in[8];
  float* out = (float*)d_out;

  char* ws = (char*)d_ws;
  constexpr size_t QKV_OFF  = 0;                       // 25165824
  constexpr size_t VT_OFF   = 25165824;                // 4194304
  constexpr size_t ATTN_OFF = VT_OFF + 4194304;        // 16777216
  constexpr size_t WT_OFF   = ATTN_OFF + 16777216;     // 12582912
  constexpr size_t BIAS_OFF = WT_OFF + 12582912;       // 12288
  constexpr size_t CTR_OFF  = BIAS_OFF + 12288;
  _Float16* QKV  = (_Float16*)(ws + QKV_OFF);
  _Float16* Vt   = (_Float16*)(ws + VT_OFF);
  _Float16* attn = (_Float16*)(ws + ATTN_OFF);
  _Float16* WT   = (_Float16*)(ws + WT_OFF);
  float*    bqkv = (float*)(ws + BIAS_OFF);
  int*      ctr  = (int*)(ws + CTR_OFF);
  _Float16* xb = (_Float16*)d_out;  // dead before final GEMM writes d_out

  cast_f32_f16<<<8192, 256, 0, stream>>>(x, xb, (2 * 2048 * 2048) / 4);
  wqkvtrans_kernel<<<dim3(48, 32), 256, 0, stream>>>(Wq, Wk, Wv, WT);
  biaspack_kernel<<<12, 256, 0, stream>>>(bq, bk, bv, bqkv);
  zeroctr_kernel<<<1, 1, 0, stream>>>(ctr);
  gemm_nt<true><<<dim3(3072 / 128, 4096 / 128), 256, 0, stream>>>(xb, WT, bqkv, QKV, 4096, 3072, 2048);
  wtrans_kernel<<<dim3(32, 32), 256, 0, stream>>>(Wo, WT, 2048, 2048, 0, 2048);
  rope_kernel<<<4096, 256, 0, stream>>>(QKV);
  vtrans_kernel<<<dim3(32, 2, 8), 256, 0, stream>>>(QKV, Vt);
  attn_kernel<<<1024, 256, 0, stream>>>(QKV, Vt, attn, ctr);
  gemm_nt<false><<<dim3(2048 / 128, 4096 / 128), 256, 0, stream>>>(attn, WT, bo, out, 4096, 2048, 2048);
}